// Round 7
// baseline (495.290 us; speedup 1.0000x reference)
//
#include <hip/hip_runtime.h>

#define N_NODES 50000
#define N_EDGES 800000
#define IN_FEAT 512
#define OUT_FEAT 128

// NUMERICS CONTRACT (R3): fp32 accumulation strictly sequential (k-order in
// GEMM, edge-order in SPMM); reassociation flips multispike floor()
// boundaries -> absmax 0.25. MLP comes from batched independent loads
// feeding in-order FMA chains.
// COMPILER CONTRACT (R5): no indexed pointer arrays -> scratch demotion.
// Named scalars / fully-unrolled constant-index arrays only.
// STRUCTURE LESSON (R2/R6): __syncthreads-bounded K-loops defeat load
// hoisting; this kernel is barrier-free so the scheduler can pipeline.

__device__ __forceinline__ float multispike(float a) {
    // floor(clamp(4x, 0, 4) + 0.5) / 4
    return floorf(fminf(fmaxf(4.0f * a, 0.0f), 4.0f) + 0.5f) * 0.25f;
}

// ---------------------------------------------------------------------------
// GEMM: C[M,128] = A[M,512] @ B[512,128], fp32, LDS-FREE + BARRIER-FREE.
// 256 threads, BM=64, thread tile 8x4 (tx=n-quad 0..31, ty=m-oct 0..7).
// Per k-quad (4 k): 8 A dwordx4 (half-wave-uniform addresses -> 2 L1 lines
// per instr) + 4 B dwordx4 (coalesced 512B, L1/L2-resident: B-slice 16KB,
// A-slice 8KB stream through L1). 128 FMAs per 12 VMEM instrs -> FMA-bound
// (VMEM ~48 cyc TA vs 256 SIMD-cyc FMA per wave). No barriers: compiler
// hoists next-iteration loads during current FMAs (what R6 couldn't do).
// k-order within each acc element is strictly sequential (b0..b3 = k+0..k+3).
// ---------------------------------------------------------------------------
__global__ __launch_bounds__(256) void gemm_kernel(const float* __restrict__ A,
                                                   const float* __restrict__ B,
                                                   float* __restrict__ C, int M) {
    const int tid = threadIdx.x;
    const int tx = tid & 31;   // n = tx*4 .. tx*4+3
    const int ty = tid >> 5;   // m = ty*8 .. ty*8+7
    const int m0 = blockIdx.x * 64 + ty * 8;

    const float4* __restrict__ A4 = (const float4*)A;   // row stride 128
    const float4* __restrict__ B4 = (const float4*)B;   // row stride 32

    // clamped row bases in float4 units (loads safe; stores guarded)
    const size_t o0 = (size_t)min(m0 + 0, M - 1) * 128;
    const size_t o1 = (size_t)min(m0 + 1, M - 1) * 128;
    const size_t o2 = (size_t)min(m0 + 2, M - 1) * 128;
    const size_t o3 = (size_t)min(m0 + 3, M - 1) * 128;
    const size_t o4 = (size_t)min(m0 + 4, M - 1) * 128;
    const size_t o5 = (size_t)min(m0 + 5, M - 1) * 128;
    const size_t o6 = (size_t)min(m0 + 6, M - 1) * 128;
    const size_t o7 = (size_t)min(m0 + 7, M - 1) * 128;

    float acc[8][4];
#pragma unroll
    for (int i = 0; i < 8; i++)
#pragma unroll
        for (int j = 0; j < 4; j++) acc[i][j] = 0.0f;

#pragma unroll 2
    for (int kb = 0; kb < 128; kb++) {      // k-quad index; k = kb*4..kb*4+3
        // 12 independent loads (issued together, no barrier in sight)
        float4 b0 = B4[(size_t)(kb * 4 + 0) * 32 + tx];
        float4 b1 = B4[(size_t)(kb * 4 + 1) * 32 + tx];
        float4 b2 = B4[(size_t)(kb * 4 + 2) * 32 + tx];
        float4 b3 = B4[(size_t)(kb * 4 + 3) * 32 + tx];
        float4 a0 = A4[o0 + kb];
        float4 a1 = A4[o1 + kb];
        float4 a2 = A4[o2 + kb];
        float4 a3 = A4[o3 + kb];
        float4 a4 = A4[o4 + kb];
        float4 a5 = A4[o5 + kb];
        float4 a6 = A4[o6 + kb];
        float4 a7 = A4[o7 + kb];

        // strict k-order per output: k+0 (a.x*b0), k+1 (a.y*b1), ...
#define ROW_FMA(i, av)                                              \
        acc[i][0] = fmaf(av.x, b0.x, acc[i][0]);                    \
        acc[i][1] = fmaf(av.x, b0.y, acc[i][1]);                    \
        acc[i][2] = fmaf(av.x, b0.z, acc[i][2]);                    \
        acc[i][3] = fmaf(av.x, b0.w, acc[i][3]);                    \
        acc[i][0] = fmaf(av.y, b1.x, acc[i][0]);                    \
        acc[i][1] = fmaf(av.y, b1.y, acc[i][1]);                    \
        acc[i][2] = fmaf(av.y, b1.z, acc[i][2]);                    \
        acc[i][3] = fmaf(av.y, b1.w, acc[i][3]);                    \
        acc[i][0] = fmaf(av.z, b2.x, acc[i][0]);                    \
        acc[i][1] = fmaf(av.z, b2.y, acc[i][1]);                    \
        acc[i][2] = fmaf(av.z, b2.z, acc[i][2]);                    \
        acc[i][3] = fmaf(av.z, b2.w, acc[i][3]);                    \
        acc[i][0] = fmaf(av.w, b3.x, acc[i][0]);                    \
        acc[i][1] = fmaf(av.w, b3.y, acc[i][1]);                    \
        acc[i][2] = fmaf(av.w, b3.z, acc[i][2]);                    \
        acc[i][3] = fmaf(av.w, b3.w, acc[i][3]);
        ROW_FMA(0, a0)
        ROW_FMA(1, a1)
        ROW_FMA(2, a2)
        ROW_FMA(3, a3)
        ROW_FMA(4, a4)
        ROW_FMA(5, a5)
        ROW_FMA(6, a6)
        ROW_FMA(7, a7)
#undef ROW_FMA
    }

#pragma unroll
    for (int i = 0; i < 8; i++) {
        int gm = m0 + i;
        if (gm < M) {
            float4 v = make_float4(acc[i][0], acc[i][1], acc[i][2], acc[i][3]);
            *(float4*)(C + (size_t)gm * OUT_FEAT + tx * 4) = v;
        }
    }
}

// ---------------------------------------------------------------------------
// row_ptr[i] = lower_bound(rows, i) over sorted rows. i in [0, N_NODES].
// ---------------------------------------------------------------------------
__global__ __launch_bounds__(256) void rowptr_kernel(const int* __restrict__ rows,
                                                     int* __restrict__ row_ptr) {
    int i = blockIdx.x * blockDim.x + threadIdx.x;
    if (i > N_NODES) return;
    int lo = 0, hi = N_EDGES;
    while (lo < hi) {
        int mid = (lo + hi) >> 1;
        if (rows[mid] < i) lo = mid + 1; else hi = mid;
    }
    row_ptr[i] = lo;
}

// ---------------------------------------------------------------------------
// SPMM + multispike (unchanged, numerics-proven absmax 0.0): one wave per
// output row, lane owns float2. Unroll x8 batched loads, ONE in-order FMA
// chain per accumulator (reference edge order).
// ---------------------------------------------------------------------------
__global__ __launch_bounds__(256) void spmm_kernel(const float* __restrict__ x,
                                                   const int* __restrict__ cols,
                                                   const float* __restrict__ ew,
                                                   const int* __restrict__ row_ptr,
                                                   float* __restrict__ out) {
    const int wave = threadIdx.x >> 6;
    const int lane = threadIdx.x & 63;
    const int r = blockIdx.x * 4 + wave;
    if (r >= N_NODES) return;

    const int e0 = row_ptr[r];
    const int e1 = row_ptr[r + 1];
    const float2* __restrict__ x2 = (const float2*)x;

    float accx = 0.0f, accy = 0.0f;
    int e = e0;
    for (; e + 8 <= e1; e += 8) {
        int c[8];
        float w[8];
        float2 v[8];
#pragma unroll
        for (int j = 0; j < 8; j++) {
            c[j] = cols[e + j];
            w[j] = ew[e + j];
        }
#pragma unroll
        for (int j = 0; j < 8; j++) {
            v[j] = x2[(size_t)c[j] * 64 + lane];
        }
#pragma unroll
        for (int j = 0; j < 8; j++) {   // strict e-order accumulation
            accx = fmaf(w[j], v[j].x, accx);
            accy = fmaf(w[j], v[j].y, accy);
        }
    }
    for (; e < e1; e++) {
        int c = cols[e];
        float w = ew[e];
        float2 v = x2[(size_t)c * 64 + lane];
        accx = fmaf(w, v.x, accx);
        accy = fmaf(w, v.y, accy);
    }
    float2* out2 = (float2*)out;
    out2[(size_t)r * 64 + lane] = make_float2(multispike(accx), multispike(accy));
}

extern "C" void kernel_launch(void* const* d_in, const int* in_sizes, int n_in,
                              void* d_out, int out_size, void* d_ws, size_t ws_size,
                              hipStream_t stream) {
    const float* feat = (const float*)d_in[0];   // [50000, 512]
    const float* weight = (const float*)d_in[1]; // [512, 128]
    const int* rows = (const int*)d_in[2];       // [800000] sorted
    const int* cols = (const int*)d_in[3];       // [800000]
    const float* ew = (const float*)d_in[4];     // [800000]
    float* out = (float*)d_out;                  // [50000, 128]

    // Workspace layout: x [50000*128 f32] then row_ptr [50001 i32]
    float* x = (float*)d_ws;
    int* row_ptr = (int*)((char*)d_ws + (size_t)N_NODES * OUT_FEAT * sizeof(float));

    rowptr_kernel<<<(N_NODES + 256) / 256, 256, 0, stream>>>(rows, row_ptr);
    gemm_kernel<<<(N_NODES + 63) / 64, 256, 0, stream>>>(feat, weight, x, N_NODES);
    spmm_kernel<<<(N_NODES + 3) / 4, 256, 0, stream>>>(x, cols, ew, row_ptr, out);
}

// Round 8
// 336.028 us; speedup vs baseline: 1.4740x; 1.4740x over previous
//
#include <hip/hip_runtime.h>

#define N_NODES 50000
#define N_EDGES 800000
#define IN_FEAT 512
#define OUT_FEAT 128

// NUMERICS CONTRACT (R3): fp32 accumulation strictly sequential per output
// element (k-order in GEMM, edge-order in SPMM); reassociation flips
// multispike floor() boundaries -> absmax 0.25. Masked FMAs with w=0 are
// exact (acc + 0*v == acc) and preserve order.
// COMPILER CONTRACT (R5/R7): the compiler will NOT hoist loads on its own
// (R7: VGPR stayed 60, VALUBusy 16%). MLP must be forced with explicitly
// NAMED batched loads feeding the in-order FMA chain (proven in spmm R4).
// STRUCTURE SCOREBOARD: R1 LDS-A+B 126us / R4 8x8 141 / R6 in-loop-global-B
// 157 / R7 no-LDS 320. This round: R1 A-staging + named-register B.

__device__ __forceinline__ float multispike(float a) {
    // floor(clamp(4x, 0, 4) + 0.5) / 4
    return floorf(fminf(fmaxf(4.0f * a, 0.0f), 4.0f) + 0.5f) * 0.25f;
}

// ---------------------------------------------------------------------------
// GEMM: C[M,128] = A[M,512] @ B[512,128], fp32 vector FMA.
// BM=64, BN=128, BK=32, 256 threads, 8x4 thread tile (R1 skeleton).
// R8: Bs-LDS eliminated. B row-slices come from global (L1/L2-resident,
// 16KB per k-tile, shared by all 782 blocks) via 8 NAMED float4 loads per
// 8-k group -> compiler must keep them in registers, 8 loads in flight.
// LDS ledger/CU/k-tile drops ~14k -> ~10k cyc (A b128 reads + A stores
// only). As padded to 68 (R2/R6-proven: conflicts 5.6M -> 2.4M).
// launch_bounds(256,3): VGPR cap ~170 == the 12.2 waves/CU grid supply.
// Same operands, same k-order as R1 -> bit-identical numerics.
// ---------------------------------------------------------------------------
__global__ __launch_bounds__(256, 3) void gemm_kernel(const float* __restrict__ A,
                                                      const float* __restrict__ B,
                                                      float* __restrict__ C, int M) {
    __shared__ float As[32][68];    // [k][m], padded

    const int tid = threadIdx.x;
    const int tx = tid & 31;   // n = tx*4 .. tx*4+3
    const int ty = tid >> 5;   // m = ty*8 .. ty*8+7
    const int block_m = blockIdx.x * 64;

    const float4* __restrict__ B4 = (const float4*)B;   // row stride 32 float4s

    float acc[8][4];
#pragma unroll
    for (int i = 0; i < 8; i++)
#pragma unroll
        for (int j = 0; j < 4; j++) acc[i][j] = 0.0f;

    for (int k0 = 0; k0 < IN_FEAT; k0 += 32) {
        // Stage A tile: 64 rows x 32 k = 512 float4 / 256 threads = 2 each.
        // Coalesced global read, transposed LDS store (R1-identical).
#pragma unroll
        for (int i = 0; i < 2; i++) {
            int f = tid + i * 256;
            int r = f >> 3;
            int kq = (f & 7) << 2;
            int gm = block_m + r;
            float4 v = make_float4(0.f, 0.f, 0.f, 0.f);
            if (gm < M) v = *(const float4*)(A + (size_t)gm * IN_FEAT + k0 + kq);
            As[kq + 0][r] = v.x;
            As[kq + 1][r] = v.y;
            As[kq + 2][r] = v.z;
            As[kq + 3][r] = v.w;
        }
        __syncthreads();

#pragma unroll
        for (int kk = 0; kk < 32; kk += 8) {
            // ---- 8 NAMED batched B loads (all independent, issued together,
            // in flight while the As reads + FMAs below execute) ----
            float4 b_0 = B4[(size_t)(k0 + kk + 0) * 32 + tx];
            float4 b_1 = B4[(size_t)(k0 + kk + 1) * 32 + tx];
            float4 b_2 = B4[(size_t)(k0 + kk + 2) * 32 + tx];
            float4 b_3 = B4[(size_t)(k0 + kk + 3) * 32 + tx];
            float4 b_4 = B4[(size_t)(k0 + kk + 4) * 32 + tx];
            float4 b_5 = B4[(size_t)(k0 + kk + 5) * 32 + tx];
            float4 b_6 = B4[(size_t)(k0 + kk + 6) * 32 + tx];
            float4 b_7 = B4[(size_t)(k0 + kk + 7) * 32 + tx];

            // strict k-order: j = 0..7 corresponds to k = k0+kk+j
#define KSTEP(J, BV)                                                    \
            {                                                           \
                float4 a0 = *(const float4*)&As[kk + J][ty * 8];        \
                float4 a1 = *(const float4*)&As[kk + J][ty * 8 + 4];    \
                float av[8] = {a0.x, a0.y, a0.z, a0.w,                  \
                               a1.x, a1.y, a1.z, a1.w};                 \
                _Pragma("unroll")                                       \
                for (int i = 0; i < 8; i++) {                           \
                    acc[i][0] = fmaf(av[i], BV.x, acc[i][0]);           \
                    acc[i][1] = fmaf(av[i], BV.y, acc[i][1]);           \
                    acc[i][2] = fmaf(av[i], BV.z, acc[i][2]);           \
                    acc[i][3] = fmaf(av[i], BV.w, acc[i][3]);           \
                }                                                       \
            }
            KSTEP(0, b_0)
            KSTEP(1, b_1)
            KSTEP(2, b_2)
            KSTEP(3, b_3)
            KSTEP(4, b_4)
            KSTEP(5, b_5)
            KSTEP(6, b_6)
            KSTEP(7, b_7)
#undef KSTEP
        }
        __syncthreads();
    }

#pragma unroll
    for (int i = 0; i < 8; i++) {
        int gm = block_m + ty * 8 + i;
        if (gm < M) {
            float4 v = make_float4(acc[i][0], acc[i][1], acc[i][2], acc[i][3]);
            *(float4*)(C + (size_t)gm * OUT_FEAT + tx * 4) = v;
        }
    }
}

// ---------------------------------------------------------------------------
// row_ptr[i] = lower_bound(rows, i) over sorted rows. i in [0, N_NODES].
// ---------------------------------------------------------------------------
__global__ __launch_bounds__(256) void rowptr_kernel(const int* __restrict__ rows,
                                                     int* __restrict__ row_ptr) {
    int i = blockIdx.x * blockDim.x + threadIdx.x;
    if (i > N_NODES) return;
    int lo = 0, hi = N_EDGES;
    while (lo < hi) {
        int mid = (lo + hi) >> 1;
        if (rows[mid] < i) lo = mid + 1; else hi = mid;
    }
    row_ptr[i] = lo;
}

// ---------------------------------------------------------------------------
// SPMM + multispike: one wave per output row, lane owns float2.
// R8: masked 16-slot blocks. Avg row = 16 edges, so R4's unroll-8 pushed
// ~half the edges through the MLP=1 remainder loop. Now EVERY edge is in a
// 16-deep batch: index clamped to e1-1, weight zeroed for slots past the
// end (exact: acc + 0*v == acc; real-edge order unchanged).
// ---------------------------------------------------------------------------
__global__ __launch_bounds__(256) void spmm_kernel(const float* __restrict__ x,
                                                   const int* __restrict__ cols,
                                                   const float* __restrict__ ew,
                                                   const int* __restrict__ row_ptr,
                                                   float* __restrict__ out) {
    const int wave = threadIdx.x >> 6;
    const int lane = threadIdx.x & 63;
    const int r = blockIdx.x * 4 + wave;
    if (r >= N_NODES) return;

    const int e0 = row_ptr[r];
    const int e1 = row_ptr[r + 1];
    const float2* __restrict__ x2 = (const float2*)x;

    float accx = 0.0f, accy = 0.0f;
    for (int eb = e0; eb < e1; eb += 16) {
        int c[16];
        float w[16];
        float2 v[16];
#pragma unroll
        for (int j = 0; j < 16; j++) {
            int idx = eb + j;
            int valid = idx < e1;
            idx = valid ? idx : (e1 - 1);
            c[j] = cols[idx];
            w[j] = valid ? ew[idx] : 0.0f;
        }
#pragma unroll
        for (int j = 0; j < 16; j++) {
            v[j] = x2[(size_t)c[j] * 64 + lane];
        }
#pragma unroll
        for (int j = 0; j < 16; j++) {   // strict e-order accumulation
            accx = fmaf(w[j], v[j].x, accx);
            accy = fmaf(w[j], v[j].y, accy);
        }
    }
    float2* out2 = (float2*)out;
    out2[(size_t)r * 64 + lane] = make_float2(multispike(accx), multispike(accy));
}

extern "C" void kernel_launch(void* const* d_in, const int* in_sizes, int n_in,
                              void* d_out, int out_size, void* d_ws, size_t ws_size,
                              hipStream_t stream) {
    const float* feat = (const float*)d_in[0];   // [50000, 512]
    const float* weight = (const float*)d_in[1]; // [512, 128]
    const int* rows = (const int*)d_in[2];       // [800000] sorted
    const int* cols = (const int*)d_in[3];       // [800000]
    const float* ew = (const float*)d_in[4];     // [800000]
    float* out = (float*)d_out;                  // [50000, 128]

    // Workspace layout: x [50000*128 f32] then row_ptr [50001 i32]
    float* x = (float*)d_ws;
    int* row_ptr = (int*)((char*)d_ws + (size_t)N_NODES * OUT_FEAT * sizeof(float));

    rowptr_kernel<<<(N_NODES + 256) / 256, 256, 0, stream>>>(rows, row_ptr);
    gemm_kernel<<<(N_NODES + 63) / 64, 256, 0, stream>>>(feat, weight, x, N_NODES);
    spmm_kernel<<<(N_NODES + 3) / 4, 256, 0, stream>>>(x, cols, ew, row_ptr, out);
}